// Round 8
// baseline (247.508 us; speedup 1.0000x reference)
//
#include <hip/hip_runtime.h>
#include <hip/hip_bf16.h>

// ConformerAttention on MI355X (gfx950), bf16 MFMA internal, fp32 in/out.
// rel_shift(ps)[i,j] == ps[i, j-i+S-1]  -> banded pos-score, never materialize [S,P].
// R8: attn restructured to wave-owns-rows (zero barriers, no combine; ones-MFMA
//     denominator normalized in-register); BK=64 GEMMs (half the barrier drains);
//     cold-path converts back to exact-RNE f2b, exact div (pk2/rcp accuracy suspects).

typedef __attribute__((ext_vector_type(8))) short  s16x8;
typedef __attribute__((ext_vector_type(8))) __bf16 bfv8;
typedef __attribute__((ext_vector_type(4))) float  f32x4;
typedef __attribute__((ext_vector_type(4))) unsigned u32x4;

__device__ __forceinline__ float b2f(short s){
  unsigned u = ((unsigned)(unsigned short)s) << 16;
  float f; __builtin_memcpy(&f, &u, 4); return f;
}
__device__ __forceinline__ short f2b(float f){          // exact RNE f32->bf16
  unsigned u; __builtin_memcpy(&u, &f, 4);
  u = (u + 0x7fffu + ((u >> 16) & 1u)) >> 16;
  return (short)u;
}
__device__ __forceinline__ unsigned pk2r(float lo, float hi){  // RNE pair pack
  return (unsigned)(unsigned short)f2b(lo) | ((unsigned)(unsigned short)f2b(hi) << 16);
}
// hw packed cvt (suspected RTZ) — used ONLY in the hot attn P-path where the
// numerator/denominator share the same rounded P (bias cancels in the ratio)
__device__ __forceinline__ unsigned pk2(float lo, float hi){
  __hip_bfloat162 t = __float22bfloat162_rn(make_float2(lo, hi));
  unsigned u; __builtin_memcpy(&u, &t, 4); return u;
}
__device__ __forceinline__ f32x4 MFMA(s16x8 a, s16x8 b, f32x4 c){
  return __builtin_amdgcn_mfma_f32_16x16x32_bf16(
      __builtin_bit_cast(bfv8, a), __builtin_bit_cast(bfv8, b), c, 0, 0, 0);
}
__device__ __forceinline__ void gload_lds16(const void* g, void* l){
  __builtin_amdgcn_global_load_lds(
      (const __attribute__((address_space(1))) void*)g,
      (__attribute__((address_space(3))) void*)l, 16, 0, 0);
}
__device__ __forceinline__ void cvt8(const float* in, short* out, size_t i8){
  f32x4 a = *(const f32x4*)(in + i8*8);
  f32x4 b = *(const f32x4*)(in + i8*8 + 4);
  u32x4 o;
  o[0] = pk2r(a[0],a[1]); o[1] = pk2r(a[2],a[3]);
  o[2] = pk2r(b[0],b[1]); o[3] = pk2r(b[2],b[3]);
  *(u32x4*)(out + i8*8) = o;
}

// ---- prep: weight/pos converts + LayerNorm, one launch ----
__global__ __launch_bounds__(256) void prep_kernel(
    const float* __restrict__ Wq, const float* __restrict__ Wk,
    const float* __restrict__ Wv, const float* __restrict__ Wo,
    const float* __restrict__ Wp, const float* __restrict__ pos,
    const float* __restrict__ x, const float* __restrict__ lnw, const float* __restrict__ lnb,
    short* __restrict__ wqkv, short* __restrict__ wo, short* __restrict__ wp,
    short* __restrict__ posbf, short* __restrict__ h_bf)
{
  int bid = blockIdx.x, tid = threadIdx.x;
  if(bid < 640){
    int w = bid >> 7;
    size_t i = (size_t)(bid & 127)*256 + tid;
    const float* src; short* dst;
    if(w == 0){ src = Wq; dst = wqkv; }
    else if(w == 1){ src = Wk; dst = wqkv + 262144; }
    else if(w == 2){ src = Wv; dst = wqkv + 524288; }
    else if(w == 3){ src = Wo; dst = wo; }
    else { src = Wp; dst = wp; }
    cvt8(src, dst, i);
  } else if(bid < 1152){
    size_t i = (size_t)(bid - 640)*256 + tid;
    if(i < 131008) cvt8(pos, posbf, i);        // 2047*512/8
  } else {
    int row = (bid - 1152)*4 + (tid >> 6);
    int lane = tid & 63;
    const float* xr = x + (size_t)row*512;
    f32x4 v0 = *(const f32x4*)(xr + lane*8);
    f32x4 v1 = *(const f32x4*)(xr + lane*8 + 4);
    float s  = v0[0]+v0[1]+v0[2]+v0[3]+v1[0]+v1[1]+v1[2]+v1[3];
    float s2 = v0[0]*v0[0]+v0[1]*v0[1]+v0[2]*v0[2]+v0[3]*v0[3]
             + v1[0]*v1[0]+v1[1]*v1[1]+v1[2]*v1[2]+v1[3]*v1[3];
    #pragma unroll
    for(int m=1;m<64;m<<=1){ s += __shfl_xor(s,m); s2 += __shfl_xor(s2,m); }
    float mu = s * (1.0f/512.0f);
    float rs = rsqrtf(s2*(1.0f/512.0f) - mu*mu + 1e-5f);
    float y[8];
    #pragma unroll
    for(int e=0;e<8;e++){
      float xv = (e<4)? v0[e] : v1[e-4];
      int d = lane*8 + e;
      y[e] = (xv - mu)*rs*lnw[d] + lnb[d];
    }
    u32x4 o;
    o[0]=pk2r(y[0],y[1]); o[1]=pk2r(y[2],y[3]); o[2]=pk2r(y[4],y[5]); o[3]=pk2r(y[6],y[7]);
    *(u32x4*)(h_bf + (size_t)row*512 + lane*8) = o;
  }
}

// ---- fused QKV GEMM (768 blocks, 128x128, BK=64) + pos GEMM (256 blocks, 64x64) ----
// Epilogue stages the C-tile through LDS and writes fragment-major q_sw/k_sw/v_sw
// chunks as coalesced 1KB wave b128 stores.
__global__ __launch_bounds__(256) void gemm_fused(
    const short* __restrict__ h_bf, const short* __restrict__ wqkv,
    const float* __restrict__ bq, const float* __restrict__ bk, const float* __restrict__ bv,
    const short* __restrict__ posbf, const short* __restrict__ wp,
    short* __restrict__ q_sw, short* __restrict__ k_sw, short* __restrict__ v_sw,
    short* __restrict__ p_sw)
{
  __shared__ __align__(16) short smem[16384];   // 32 KB: At|Bt (BK=64), then C staging
  short* At = smem;
  short* Bt = smem + 8192;
  int bid = blockIdx.x, tid = threadIdx.x;
  int wave = tid >> 6, lane = tid & 63;
  int quad = lane >> 4, l16 = lane & 15;
  if(bid < 768){
    int bx = bid % 12, by = bid / 12;
    int m0 = by*128, n0 = bx*128;
    int wm = wave >> 1, wn = wave & 1;
    int sr8 = lane >> 3, sc = (lane & 7)*8;
    f32x4 acc[4][4] = {};
    for(int k0=0; k0<512; k0+=64){
      #pragma unroll
      for(int c=0;c<4;c++){
        int ci = wave*4 + c;                     // chunk: rows ci*8..ci*8+7
        gload_lds16(h_bf + (size_t)(m0 + ci*8 + sr8)*512 + k0 + sc, At + ci*512);
        gload_lds16(wqkv + (size_t)(n0 + ci*8 + sr8)*512 + k0 + sc, Bt + ci*512);
      }
      __syncthreads();
      #pragma unroll
      for(int ks2=0;ks2<2;ks2++){
        s16x8 af[4], bfr[4];
        #pragma unroll
        for(int i=0;i<4;i++) af[i]  = *(const s16x8*)(At + (wm*64 + i*16 + l16)*64 + ks2*32 + quad*8);
        #pragma unroll
        for(int j=0;j<4;j++) bfr[j] = *(const s16x8*)(Bt + (wn*64 + j*16 + l16)*64 + ks2*32 + quad*8);
        #pragma unroll
        for(int i=0;i<4;i++)
          #pragma unroll
          for(int j=0;j<4;j++)
            acc[i][j] = MFMA(af[i], bfr[j], acc[i][j]);
      }
      __syncthreads();
    }
    int seg = bx >> 2;               // 0 q, 1 k, 2 v (uniform per block)
    int nseg = (bx & 3)*128;
    int bb = by >> 3;
    const float* bsrc = (seg==0)? bq : (seg==1)? bk : bv;
    float bias_j[4];
    #pragma unroll
    for(int j=0;j<4;j++) bias_j[j] = bsrc[nseg + wn*64 + j*16 + l16];
    if(seg < 2){
      short* dst = seg ? k_sw : q_sw;
      #pragma unroll
      for(int h2=0; h2<2; h2++){
        if(wm == h2){
          #pragma unroll
          for(int i=0;i<4;i++){
            int lr = i*16 + quad*4;
            #pragma unroll
            for(int j=0;j<4;j++){
              int cl = wn*64 + j*16 + l16;
              unsigned p01 = pk2r(acc[i][j][0]+bias_j[j], acc[i][j][1]+bias_j[j]);
              unsigned p23 = pk2r(acc[i][j][2]+bias_j[j], acc[i][j][3]+bias_j[j]);
              smem[(lr+0)*136 + cl] = (short)p01;
              smem[(lr+1)*136 + cl] = (short)(p01>>16);
              smem[(lr+2)*136 + cl] = (short)p23;
              smem[(lr+3)*136 + cl] = (short)(p23>>16);
            }
          }
        }
        __syncthreads();
        #pragma unroll
        for(int it=0; it<4; it++){
          int ci = it*4 + wave;              // hs = ci>>2 (head/ks slot), tb = ci&3
          int hs = ci >> 2, tb = ci & 3;
          s16x8 vv = *(const s16x8*)(smem + (tb*16 + l16)*136 + hs*32 + quad*8);
          int hh = (nseg>>6) + (hs>>1);
          int tg = ((m0 + h2*64)>>4) + tb;
          size_t chunk = ((size_t)((bb*8 + hh)*64 + tg))*2 + (hs&1);
          *(s16x8*)(dst + chunk*512 + (size_t)lane*8) = vv;
        }
        __syncthreads();
      }
    } else {
      // V: stage transposed Ct_v[dim 0..127][token 0..63], stride 72
      #pragma unroll
      for(int h2=0; h2<2; h2++){
        int jt = by*2 + h2;
        if(wm == h2){
          #pragma unroll
          for(int i=0;i<4;i++){
            int tl = i*16 + quad*4;
            #pragma unroll
            for(int j=0;j<4;j++){
              int dl = wn*64 + j*16 + l16;
              unsigned p01 = pk2r(acc[i][j][0]+bias_j[j], acc[i][j][1]+bias_j[j]);
              unsigned p23 = pk2r(acc[i][j][2]+bias_j[j], acc[i][j][3]+bias_j[j]);
              unsigned* w2 = (unsigned*)(smem + dl*72 + tl);
              w2[0] = p01; w2[1] = p23;
            }
          }
        }
        __syncthreads();
        #pragma unroll
        for(int it=0; it<4; it++){
          int ci = it*4 + wave;              // ci = hl*8 + ds*2 + jk
          int hl = ci>>3, ds = (ci>>1)&3, jk = ci&1;
          s16x8 vv = *(const s16x8*)(smem + (hl*64 + ds*16 + l16)*72 + jk*32 + quad*8);
          int hh = (nseg>>6) + hl;
          size_t chunk = (((size_t)((bb*8 + hh)*16 + jt))*4 + ds)*2 + jk;
          *(s16x8*)(v_sw + chunk*512 + (size_t)lane*8) = vv;
        }
        __syncthreads();
      }
    }
  } else {
    // pos projection: [2048,512] = posbf(2047 rows, clamped) @ wp^T, 64x64, BK=32
    short* Bt2 = smem + 2048;
    int pid = bid - 768;
    int bx = pid % 8, by = pid / 8;
    int m0 = by*64, n0 = bx*64;
    int wm = wave >> 1, wn = wave & 1;
    int srow = lane >> 2, scol = (lane & 3)*8;
    f32x4 acc[2][2] = {};
    for(int k0=0; k0<512; k0+=32){
      int rb = wave*16;
      int ra = m0 + rb + srow; if(ra > 2046) ra = 2046;
      gload_lds16(posbf + (size_t)ra*512 + k0 + scol, At + rb*32);
      gload_lds16(wp + (size_t)(n0 + rb + srow)*512 + k0 + scol, Bt2 + rb*32);
      __syncthreads();
      s16x8 af[2], bfr[2];
      #pragma unroll
      for(int i=0;i<2;i++) af[i]  = *(const s16x8*)(At + (wm*32 + i*16 + l16)*32 + quad*8);
      #pragma unroll
      for(int j=0;j<2;j++) bfr[j] = *(const s16x8*)(Bt2 + (wn*32 + j*16 + l16)*32 + quad*8);
      #pragma unroll
      for(int i=0;i<2;i++)
        #pragma unroll
        for(int j=0;j<2;j++)
          acc[i][j] = MFMA(af[i], bfr[j], acc[i][j]);
      __syncthreads();
    }
    #pragma unroll
    for(int i=0;i<2;i++){
      int rowb = m0 + wm*32 + i*16 + quad*4;          // rowb&15 = quad*4
      #pragma unroll
      for(int j=0;j<2;j++){
        int col = n0 + wn*32 + j*16 + l16;
        int hh = col>>6, ks = (col>>5)&1, qd = (col>>3)&3, e = col&7;
        int rblk = rowb>>4;
        size_t base = ((size_t)(((hh*128+rblk)*2+ks)*64) + qd*16)*8 + e;
        #pragma unroll
        for(int r=0;r<4;r++)
          p_sw[base + (size_t)(quad*4+r)*8] = f2b(acc[i][j][r]);
      }
    }
  }
}

// ---- Fused rel-pos attention: grid(16,8,8), 4 waves/block, wave owns 16 q-rows
// and iterates ALL 16 jt. Zero barriers; LDS wave-private P tile only.
// Linear (no-max) softmax; rotated pos-score as QK C-init; denominator via
// ones-splat PV MFMA, normalized in-register.
__global__ __launch_bounds__(256) void attn_kernel(
    const short* __restrict__ q_sw, const short* __restrict__ k_sw,
    const short* __restrict__ v_sw, const short* __restrict__ p_sw,
    const float* __restrict__ bu, const float* __restrict__ bvv,
    short* __restrict__ out)
{
  __shared__ __align__(16) short pwall[4*1152];   // 9216 B, per-wave P tiles
  int tid = threadIdx.x;
  int wave = tid >> 6, lane = tid & 63, quad = lane >> 4, l16 = lane & 15;
  int h = blockIdx.y, b = blockIdx.z, bh = b*8 + h;
  int iw = blockIdx.x*64 + wave*16;
  int tblk = blockIdx.x*4 + wave;
  short* pw = pwall + wave*1152;

  const short* qb = q_sw + (size_t)bh*65536;
  const short* kb = k_sw + (size_t)bh*65536;
  const short* vb = v_sw + (size_t)bh*65536;
  const short* pb = p_sw + (size_t)h*131072;

  // q fragments; bias + exact 0.125 scale folded
  s16x8 qu[2], qv[2];
  #pragma unroll
  for(int ks=0;ks<2;ks++){
    s16x8 qr = *(const s16x8*)(qb + ((size_t)(tblk*2+ks)*64 + lane)*8);
    short tu[8], tv[8];
    #pragma unroll
    for(int e=0;e<8;e++){
      int d = h*64 + ks*32 + quad*8 + e;
      float f = b2f(qr[e]);
      tu[e] = f2b((f + bu[d]) * 0.125f);
      tv[e] = f2b((f + bvv[d]) * 0.125f);
    }
    qu[ks] = *(s16x8*)tu; qv[ks] = *(s16x8*)tv;
  }

  // ones splat for the denominator MFMA (bf16 1.0 = 0x3F80)
  s16x8 ones;
  #pragma unroll
  for(int e=0;e<8;e++) ones[e] = (short)0x3F80;

  // hoisted band-gather controls (per accumulator register r)
  int srcl[4]; bool lo[4];
  #pragma unroll
  for(int r=0;r<4;r++){
    int il = quad*4 + r;
    srcl[r] = quad*16 + ((l16 + 15 - il) & 15);
    lo[r]   = (l16 <= il);
  }

  f32x4 oacc[4] = {};
  f32x4 lacc = {};

  #pragma unroll 2
  for(int jt=0; jt<16; jt++){
    // banded pos scores: 5 row-blocks starting at rb0 (coalesced)
    int rb0 = (jt*64 - iw + 1008) >> 4;
    f32x4 ps[5];
    #pragma unroll
    for(int nt=0;nt<5;nt++){
      f32x4 a = {};
      #pragma unroll
      for(int ks=0;ks<2;ks++){
        s16x8 pf = *(const s16x8*)(pb + ((size_t)((rb0+nt)*2+ks)*64 + lane)*8);
        a = MFMA(qv[ks], pf, a);
      }
      ps[nt] = a;
    }
    // rotate band lanes
    float rot[4][5];
    #pragma unroll
    for(int r=0;r<4;r++)
      #pragma unroll
      for(int nt=0;nt<5;nt++) rot[r][nt] = __shfl(ps[nt][r], srcl[r]);
    // content scores with rotated pos-score as C-init; exp
    float pe[4][4];
    #pragma unroll
    for(int js=0;js<4;js++){
      f32x4 a;
      #pragma unroll
      for(int r=0;r<4;r++) a[r] = lo[r] ? rot[r][js] : rot[r][js+1];
      #pragma unroll
      for(int ks=0;ks<2;ks++){
        s16x8 kf = *(const s16x8*)(kb + ((size_t)((jt*4+js)*2+ks)*64 + lane)*8);
        a = MFMA(qu[ks], kf, a);
      }
      #pragma unroll
      for(int r=0;r<4;r++) pe[js][r] = __expf(a[r]);
    }
    // P -> LDS (PV A-layout source), hw packed converts (hot path)
    #pragma unroll
    for(int js=0;js<4;js++){
      int col = js*16 + l16;
      unsigned p01 = pk2(pe[js][0], pe[js][1]);
      unsigned p23 = pk2(pe[js][2], pe[js][3]);
      pw[(quad*4+0)*72 + col] = (short)p01;
      pw[(quad*4+1)*72 + col] = (short)(p01>>16);
      pw[(quad*4+2)*72 + col] = (short)p23;
      pw[(quad*4+3)*72 + col] = (short)(p23>>16);
    }
    // PV: 2 j-ksteps x (4 d-subtiles + ones row-sum)
    #pragma unroll
    for(int jk=0;jk<2;jk++){
      s16x8 pf = *(const s16x8*)(pw + l16*72 + jk*32 + quad*8);
      #pragma unroll
      for(int ds=0;ds<4;ds++){
        s16x8 vf = *(const s16x8*)(vb + ((size_t)((jt*4+ds)*2+jk)*64 + lane)*8);
        oacc[ds] = MFMA(pf, vf, oacc[ds]);
      }
      lacc = MFMA(pf, ones, lacc);
    }
  }
  // epilogue: every lane holds its rows' denominators (C cols all equal)
  float rl[4];
  #pragma unroll
  for(int r=0;r<4;r++) rl[r] = 1.0f / lacc[r];
  #pragma unroll
  for(int ds=0; ds<4; ds++){
    #pragma unroll
    for(int r=0;r<4;r++){
      int row = iw + quad*4 + r;
      out[((size_t)(b*1024 + row)*512) + h*64 + ds*16 + l16] = f2b(oacc[ds][r] * rl[r]);
    }
  }
}

// ---- out projection: fp32 out = a_bf @ Wo^T + bo + x, 64x64 tiles, BK=64 ----
__global__ __launch_bounds__(256) void gemm_out(
    const short* __restrict__ A, const short* __restrict__ B,
    const float* __restrict__ bias, const float* __restrict__ resid,
    float* __restrict__ Cout)
{
  __shared__ __align__(16) short At[64*64];
  __shared__ __align__(16) short Bt[64*64];
  int tid = threadIdx.x;
  int wave = tid >> 6, lane = tid & 63;
  int quad = lane >> 4, l16 = lane & 15;
  int wm = wave >> 1, wn = wave & 1;
  int m0 = blockIdx.y*64, n0 = blockIdx.x*64;
  int sr8 = lane >> 3, sc = (lane & 7)*8;
  f32x4 acc[2][2] = {};
  for(int k0=0; k0<512; k0+=64){
    #pragma unroll
    for(int c=0;c<2;c++){
      int ci = wave*2 + c;                     // chunk: rows ci*8..ci*8+7
      gload_lds16(A + (size_t)(m0 + ci*8 + sr8)*512 + k0 + sc, At + ci*512);
      gload_lds16(B + (size_t)(n0 + ci*8 + sr8)*512 + k0 + sc, Bt + ci*512);
    }
    __syncthreads();
    #pragma unroll
    for(int ks2=0;ks2<2;ks2++){
      s16x8 af[2], bfr[2];
      #pragma unroll
      for(int i=0;i<2;i++) af[i]  = *(const s16x8*)(At + (wm*32 + i*16 + l16)*64 + ks2*32 + quad*8);
      #pragma unroll
      for(int j=0;j<2;j++) bfr[j] = *(const s16x8*)(Bt + (wn*32 + j*16 + l16)*64 + ks2*32 + quad*8);
      #pragma unroll
      for(int i=0;i<2;i++)
        #pragma unroll
        for(int j=0;j<2;j++)
          acc[i][j] = MFMA(af[i], bfr[j], acc[i][j]);
    }
    __syncthreads();
  }
  #pragma unroll
  for(int i=0;i<2;i++){
    int rowb = m0 + wm*32 + i*16 + quad*4;
    #pragma unroll
    for(int j=0;j<2;j++){
      int col = n0 + wn*32 + j*16 + l16;
      float bv = bias[col];
      #pragma unroll
      for(int r=0;r<4;r++){
        size_t idx = (size_t)(rowb + r)*512 + col;
        Cout[idx] = acc[i][j][r] + bv + resid[idx];
      }
    }
  }
}

extern "C" void kernel_launch(void* const* d_in, const int* in_sizes, int n_in,
                              void* d_out, int out_size, void* d_ws, size_t ws_size,
                              hipStream_t stream)
{
  const float* x    = (const float*)d_in[0];
  const float* pos  = (const float*)d_in[1];
  const float* lnw  = (const float*)d_in[2];
  const float* lnb  = (const float*)d_in[3];
  const float* Wq   = (const float*)d_in[4];
  const float* bq   = (const float*)d_in[5];
  const float* Wk   = (const float*)d_in[6];
  const float* bk   = (const float*)d_in[7];
  const float* Wv   = (const float*)d_in[8];
  const float* bv   = (const float*)d_in[9];
  const float* Wo   = (const float*)d_in[10];
  const float* bo   = (const float*)d_in[11];
  const float* Wp   = (const float*)d_in[12];
  const float* pbu  = (const float*)d_in[13];
  const float* pbv  = (const float*)d_in[14];
  float* out = (float*)d_out;

  char* ws = (char*)d_ws;
  short* h_bf    = (short*)(ws);                 // 8192x512
  short* q_sw    = (short*)(ws + ( 8u<<20));     // fragment-major
  short* k_sw    = (short*)(ws + (16u<<20));
  short* v_sw    = (short*)(ws + (24u<<20));
  short* a_bf    = (short*)(ws + (32u<<20));     // attn out, row-major
  short* p_sw    = (short*)(ws + (40u<<20));     // 2 MB
  short* pos_bf  = (short*)(ws + (42u<<20));     // 2 MB
  short* wqkv_bf = (short*)(ws + (44u<<20));     // 3 MB
  short* wo_bf   = (short*)(ws + (47u<<20));     // 0.5 MB
  short* wp_bf   = (short*)(ws + (47u<<20) + (512u<<10));

  prep_kernel<<<dim3(3200), 256, 0, stream>>>(Wq, Wk, Wv, Wo, Wp, pos,
                                              x, lnw, lnb,
                                              wqkv_bf, wo_bf, wp_bf, pos_bf, h_bf);
  gemm_fused<<<dim3(1024), 256, 0, stream>>>(h_bf, wqkv_bf, bq, bk, bv,
                                             pos_bf, wp_bf,
                                             q_sw, k_sw, v_sw, p_sw);
  attn_kernel<<<dim3(16,8,8), 256, 0, stream>>>(q_sw, k_sw, v_sw, p_sw, pbu, pbv, a_bf);
  gemm_out<<<dim3(8,128), 256, 0, stream>>>(a_bf, wo_bf, bo, x, out);
  (void)in_sizes; (void)n_in; (void)out_size; (void)ws_size;
}

// Round 9
// 213.647 us; speedup vs baseline: 1.1585x; 1.1585x over previous
//
#include <hip/hip_runtime.h>
#include <hip/hip_bf16.h>

// ConformerAttention on MI355X (gfx950), bf16 MFMA internal, fp32 in/out.
// rel_shift(ps)[i,j] == ps[i, j-i+S-1]  -> banded pos-score, never materialize [S,P].
// R9: revert attn to R7 split-j structure (16384 waves — TLP is king for this
//     latency-bound kernel; R8's 4096-wave variant regressed 77->114 us).
//     Keep BK=64 GEMMs. Accuracy experiment: hot-path P converts -> software RNE
//     (pk2r), exact division in epilogue.

typedef __attribute__((ext_vector_type(8))) short  s16x8;
typedef __attribute__((ext_vector_type(8))) __bf16 bfv8;
typedef __attribute__((ext_vector_type(4))) float  f32x4;
typedef __attribute__((ext_vector_type(4))) unsigned u32x4;

__device__ __forceinline__ float b2f(short s){
  unsigned u = ((unsigned)(unsigned short)s) << 16;
  float f; __builtin_memcpy(&f, &u, 4); return f;
}
__device__ __forceinline__ short f2b(float f){          // exact RNE f32->bf16
  unsigned u; __builtin_memcpy(&u, &f, 4);
  u = (u + 0x7fffu + ((u >> 16) & 1u)) >> 16;
  return (short)u;
}
__device__ __forceinline__ unsigned pk2r(float lo, float hi){  // RNE pair pack
  return (unsigned)(unsigned short)f2b(lo) | ((unsigned)(unsigned short)f2b(hi) << 16);
}
__device__ __forceinline__ f32x4 MFMA(s16x8 a, s16x8 b, f32x4 c){
  return __builtin_amdgcn_mfma_f32_16x16x32_bf16(
      __builtin_bit_cast(bfv8, a), __builtin_bit_cast(bfv8, b), c, 0, 0, 0);
}
__device__ __forceinline__ void gload_lds16(const void* g, void* l){
  __builtin_amdgcn_global_load_lds(
      (const __attribute__((address_space(1))) void*)g,
      (__attribute__((address_space(3))) void*)l, 16, 0, 0);
}
__device__ __forceinline__ void cvt8(const float* in, short* out, size_t i8){
  f32x4 a = *(const f32x4*)(in + i8*8);
  f32x4 b = *(const f32x4*)(in + i8*8 + 4);
  u32x4 o;
  o[0] = pk2r(a[0],a[1]); o[1] = pk2r(a[2],a[3]);
  o[2] = pk2r(b[0],b[1]); o[3] = pk2r(b[2],b[3]);
  *(u32x4*)(out + i8*8) = o;
}

// ---- prep: weight/pos converts + LayerNorm, one launch ----
__global__ __launch_bounds__(256) void prep_kernel(
    const float* __restrict__ Wq, const float* __restrict__ Wk,
    const float* __restrict__ Wv, const float* __restrict__ Wo,
    const float* __restrict__ Wp, const float* __restrict__ pos,
    const float* __restrict__ x, const float* __restrict__ lnw, const float* __restrict__ lnb,
    short* __restrict__ wqkv, short* __restrict__ wo, short* __restrict__ wp,
    short* __restrict__ posbf, short* __restrict__ h_bf)
{
  int bid = blockIdx.x, tid = threadIdx.x;
  if(bid < 640){
    int w = bid >> 7;
    size_t i = (size_t)(bid & 127)*256 + tid;
    const float* src; short* dst;
    if(w == 0){ src = Wq; dst = wqkv; }
    else if(w == 1){ src = Wk; dst = wqkv + 262144; }
    else if(w == 2){ src = Wv; dst = wqkv + 524288; }
    else if(w == 3){ src = Wo; dst = wo; }
    else { src = Wp; dst = wp; }
    cvt8(src, dst, i);
  } else if(bid < 1152){
    size_t i = (size_t)(bid - 640)*256 + tid;
    if(i < 131008) cvt8(pos, posbf, i);        // 2047*512/8
  } else {
    int row = (bid - 1152)*4 + (tid >> 6);
    int lane = tid & 63;
    const float* xr = x + (size_t)row*512;
    f32x4 v0 = *(const f32x4*)(xr + lane*8);
    f32x4 v1 = *(const f32x4*)(xr + lane*8 + 4);
    float s  = v0[0]+v0[1]+v0[2]+v0[3]+v1[0]+v1[1]+v1[2]+v1[3];
    float s2 = v0[0]*v0[0]+v0[1]*v0[1]+v0[2]*v0[2]+v0[3]*v0[3]
             + v1[0]*v1[0]+v1[1]*v1[1]+v1[2]*v1[2]+v1[3]*v1[3];
    #pragma unroll
    for(int m=1;m<64;m<<=1){ s += __shfl_xor(s,m); s2 += __shfl_xor(s2,m); }
    float mu = s * (1.0f/512.0f);
    float rs = rsqrtf(s2*(1.0f/512.0f) - mu*mu + 1e-5f);
    float y[8];
    #pragma unroll
    for(int e=0;e<8;e++){
      float xv = (e<4)? v0[e] : v1[e-4];
      int d = lane*8 + e;
      y[e] = (xv - mu)*rs*lnw[d] + lnb[d];
    }
    u32x4 o;
    o[0]=pk2r(y[0],y[1]); o[1]=pk2r(y[2],y[3]); o[2]=pk2r(y[4],y[5]); o[3]=pk2r(y[6],y[7]);
    *(u32x4*)(h_bf + (size_t)row*512 + lane*8) = o;
  }
}

// ---- fused QKV GEMM (768 blocks, 128x128, BK=64) + pos GEMM (256 blocks, 64x64) ----
__global__ __launch_bounds__(256) void gemm_fused(
    const short* __restrict__ h_bf, const short* __restrict__ wqkv,
    const float* __restrict__ bq, const float* __restrict__ bk, const float* __restrict__ bv,
    const short* __restrict__ posbf, const short* __restrict__ wp,
    short* __restrict__ q_sw, short* __restrict__ k_sw, short* __restrict__ v_sw,
    short* __restrict__ p_sw)
{
  __shared__ __align__(16) short smem[16384];   // 32 KB: At|Bt (BK=64), then C staging
  short* At = smem;
  short* Bt = smem + 8192;
  int bid = blockIdx.x, tid = threadIdx.x;
  int wave = tid >> 6, lane = tid & 63;
  int quad = lane >> 4, l16 = lane & 15;
  if(bid < 768){
    int bx = bid % 12, by = bid / 12;
    int m0 = by*128, n0 = bx*128;
    int wm = wave >> 1, wn = wave & 1;
    int sr8 = lane >> 3, sc = (lane & 7)*8;
    f32x4 acc[4][4] = {};
    for(int k0=0; k0<512; k0+=64){
      #pragma unroll
      for(int c=0;c<4;c++){
        int ci = wave*4 + c;                     // chunk: rows ci*8..ci*8+7
        gload_lds16(h_bf + (size_t)(m0 + ci*8 + sr8)*512 + k0 + sc, At + ci*512);
        gload_lds16(wqkv + (size_t)(n0 + ci*8 + sr8)*512 + k0 + sc, Bt + ci*512);
      }
      __syncthreads();
      #pragma unroll
      for(int ks2=0;ks2<2;ks2++){
        s16x8 af[4], bfr[4];
        #pragma unroll
        for(int i=0;i<4;i++) af[i]  = *(const s16x8*)(At + (wm*64 + i*16 + l16)*64 + ks2*32 + quad*8);
        #pragma unroll
        for(int j=0;j<4;j++) bfr[j] = *(const s16x8*)(Bt + (wn*64 + j*16 + l16)*64 + ks2*32 + quad*8);
        #pragma unroll
        for(int i=0;i<4;i++)
          #pragma unroll
          for(int j=0;j<4;j++)
            acc[i][j] = MFMA(af[i], bfr[j], acc[i][j]);
      }
      __syncthreads();
    }
    int seg = bx >> 2;               // 0 q, 1 k, 2 v (uniform per block)
    int nseg = (bx & 3)*128;
    int bb = by >> 3;
    const float* bsrc = (seg==0)? bq : (seg==1)? bk : bv;
    float bias_j[4];
    #pragma unroll
    for(int j=0;j<4;j++) bias_j[j] = bsrc[nseg + wn*64 + j*16 + l16];
    if(seg < 2){
      short* dst = seg ? k_sw : q_sw;
      #pragma unroll
      for(int h2=0; h2<2; h2++){
        if(wm == h2){
          #pragma unroll
          for(int i=0;i<4;i++){
            int lr = i*16 + quad*4;
            #pragma unroll
            for(int j=0;j<4;j++){
              int cl = wn*64 + j*16 + l16;
              unsigned p01 = pk2r(acc[i][j][0]+bias_j[j], acc[i][j][1]+bias_j[j]);
              unsigned p23 = pk2r(acc[i][j][2]+bias_j[j], acc[i][j][3]+bias_j[j]);
              smem[(lr+0)*136 + cl] = (short)p01;
              smem[(lr+1)*136 + cl] = (short)(p01>>16);
              smem[(lr+2)*136 + cl] = (short)p23;
              smem[(lr+3)*136 + cl] = (short)(p23>>16);
            }
          }
        }
        __syncthreads();
        #pragma unroll
        for(int it=0; it<4; it++){
          int ci = it*4 + wave;              // hs = ci>>2 (head/ks slot), tb = ci&3
          int hs = ci >> 2, tb = ci & 3;
          s16x8 vv = *(const s16x8*)(smem + (tb*16 + l16)*136 + hs*32 + quad*8);
          int hh = (nseg>>6) + (hs>>1);
          int tg = ((m0 + h2*64)>>4) + tb;
          size_t chunk = ((size_t)((bb*8 + hh)*64 + tg))*2 + (hs&1);
          *(s16x8*)(dst + chunk*512 + (size_t)lane*8) = vv;
        }
        __syncthreads();
      }
    } else {
      // V: stage transposed Ct_v[dim 0..127][token 0..63], stride 72
      #pragma unroll
      for(int h2=0; h2<2; h2++){
        int jt = by*2 + h2;
        if(wm == h2){
          #pragma unroll
          for(int i=0;i<4;i++){
            int tl = i*16 + quad*4;
            #pragma unroll
            for(int j=0;j<4;j++){
              int dl = wn*64 + j*16 + l16;
              unsigned p01 = pk2r(acc[i][j][0]+bias_j[j], acc[i][j][1]+bias_j[j]);
              unsigned p23 = pk2r(acc[i][j][2]+bias_j[j], acc[i][j][3]+bias_j[j]);
              unsigned* w2 = (unsigned*)(smem + dl*72 + tl);
              w2[0] = p01; w2[1] = p23;
            }
          }
        }
        __syncthreads();
        #pragma unroll
        for(int it=0; it<4; it++){
          int ci = it*4 + wave;              // ci = hl*8 + ds*2 + jk
          int hl = ci>>3, ds = (ci>>1)&3, jk = ci&1;
          s16x8 vv = *(const s16x8*)(smem + (hl*64 + ds*16 + l16)*72 + jk*32 + quad*8);
          int hh = (nseg>>6) + hl;
          size_t chunk = (((size_t)((bb*8 + hh)*16 + jt))*4 + ds)*2 + jk;
          *(s16x8*)(v_sw + chunk*512 + (size_t)lane*8) = vv;
        }
        __syncthreads();
      }
    }
  } else {
    // pos projection: [2048,512] = posbf(2047 rows, clamped) @ wp^T, 64x64, BK=32
    short* Bt2 = smem + 2048;
    int pid = bid - 768;
    int bx = pid % 8, by = pid / 8;
    int m0 = by*64, n0 = bx*64;
    int wm = wave >> 1, wn = wave & 1;
    int srow = lane >> 2, scol = (lane & 3)*8;
    f32x4 acc[2][2] = {};
    for(int k0=0; k0<512; k0+=32){
      int rb = wave*16;
      int ra = m0 + rb + srow; if(ra > 2046) ra = 2046;
      gload_lds16(posbf + (size_t)ra*512 + k0 + scol, At + rb*32);
      gload_lds16(wp + (size_t)(n0 + rb + srow)*512 + k0 + scol, Bt2 + rb*32);
      __syncthreads();
      s16x8 af[2], bfr[2];
      #pragma unroll
      for(int i=0;i<2;i++) af[i]  = *(const s16x8*)(At + (wm*32 + i*16 + l16)*32 + quad*8);
      #pragma unroll
      for(int j=0;j<2;j++) bfr[j] = *(const s16x8*)(Bt2 + (wn*32 + j*16 + l16)*32 + quad*8);
      #pragma unroll
      for(int i=0;i<2;i++)
        #pragma unroll
        for(int j=0;j<2;j++)
          acc[i][j] = MFMA(af[i], bfr[j], acc[i][j]);
      __syncthreads();
    }
    #pragma unroll
    for(int i=0;i<2;i++){
      int rowb = m0 + wm*32 + i*16 + quad*4;          // rowb&15 = quad*4
      #pragma unroll
      for(int j=0;j<2;j++){
        int col = n0 + wn*32 + j*16 + l16;
        int hh = col>>6, ks = (col>>5)&1, qd = (col>>3)&3, e = col&7;
        int rblk = rowb>>4;
        size_t base = ((size_t)(((hh*128+rblk)*2+ks)*64) + qd*16)*8 + e;
        #pragma unroll
        for(int r=0;r<4;r++)
          p_sw[base + (size_t)(quad*4+r)*8] = f2b(acc[i][j][r]);
      }
    }
  }
}

// ---- Fused rel-pos attention: grid(64,8,8), 4 waves/block; wave w owns 16 q-rows
// for jt w*4..w*4+3 (split-j, 16384 waves for TLP). Linear no-max softmax; rotated
// pos-score as QK C-init; denominator via ones-splat PV MFMA; additive LDS combine.
__global__ __launch_bounds__(256) void attn_kernel(
    const short* __restrict__ q_sw, const short* __restrict__ k_sw,
    const short* __restrict__ v_sw, const short* __restrict__ p_sw,
    const float* __restrict__ bu, const float* __restrict__ bvv,
    short* __restrict__ out)
{
  __shared__ __align__(16) float combf[4160];   // 16640 B; waves' pw tiles overlay front
  int tid = threadIdx.x;
  int wave = tid >> 6, lane = tid & 63, quad = lane >> 4, l16 = lane & 15;
  int h = blockIdx.y, b = blockIdx.z, bh = b*8 + h;
  int iblk = blockIdx.x;                 // 16-row q tile
  int iw = iblk*16;
  short* pw = (short*)combf + wave*1152; // 16*72 bf16 P tile

  const short* qb = q_sw + (size_t)bh*65536;
  const short* kb = k_sw + (size_t)bh*65536;
  const short* vb = v_sw + (size_t)bh*65536;
  const short* pb = p_sw + (size_t)h*131072;

  // q fragments; bias + exact 0.125 scale folded
  s16x8 qu[2], qv[2];
  #pragma unroll
  for(int ks=0;ks<2;ks++){
    s16x8 qr = *(const s16x8*)(qb + ((size_t)(iblk*2+ks)*64 + lane)*8);
    short tu[8], tv[8];
    #pragma unroll
    for(int e=0;e<8;e++){
      int d = h*64 + ks*32 + quad*8 + e;
      float f = b2f(qr[e]);
      tu[e] = f2b((f + bu[d]) * 0.125f);
      tv[e] = f2b((f + bvv[d]) * 0.125f);
    }
    qu[ks] = *(s16x8*)tu; qv[ks] = *(s16x8*)tv;
  }

  // ones splat for the denominator MFMA (bf16 1.0 = 0x3F80)
  s16x8 ones;
  #pragma unroll
  for(int e=0;e<8;e++) ones[e] = (short)0x3F80;

  // hoisted band-gather controls (per accumulator register r)
  int srcl[4]; bool lo[4];
  #pragma unroll
  for(int r=0;r<4;r++){
    int il = quad*4 + r;
    srcl[r] = quad*16 + ((l16 + 15 - il) & 15);
    lo[r]   = (l16 <= il);
  }

  f32x4 oacc[4] = {};
  f32x4 lacc = {};

  #pragma unroll
  for(int t=0; t<4; t++){
    int jt = wave*4 + t;
    // banded pos scores: 5 row-blocks starting at rb0 (coalesced)
    int rb0 = (jt*64 - iw + 1008) >> 4;
    f32x4 ps[5];
    #pragma unroll
    for(int nt=0;nt<5;nt++){
      f32x4 a = {};
      #pragma unroll
      for(int ks=0;ks<2;ks++){
        s16x8 pf = *(const s16x8*)(pb + ((size_t)((rb0+nt)*2+ks)*64 + lane)*8);
        a = MFMA(qv[ks], pf, a);
      }
      ps[nt] = a;
    }
    // rotate band lanes
    float rot[4][5];
    #pragma unroll
    for(int r=0;r<4;r++)
      #pragma unroll
      for(int nt=0;nt<5;nt++) rot[r][nt] = __shfl(ps[nt][r], srcl[r]);
    // content scores with rotated pos-score as C-init; exp
    float pe[4][4];
    #pragma unroll
    for(int js=0;js<4;js++){
      f32x4 a;
      #pragma unroll
      for(int r=0;r<4;r++) a[r] = lo[r] ? rot[r][js] : rot[r][js+1];
      #pragma unroll
      for(int ks=0;ks<2;ks++){
        s16x8 kf = *(const s16x8*)(kb + ((size_t)((jt*4+js)*2+ks)*64 + lane)*8);
        a = MFMA(qu[ks], kf, a);
      }
      #pragma unroll
      for(int r=0;r<4;r++) pe[js][r] = __expf(a[r]);
    }
    // P -> LDS (PV A-layout source), RNE converts
    #pragma unroll
    for(int js=0;js<4;js++){
      int col = js*16 + l16;
      unsigned p01 = pk2r(pe[js][0], pe[js][1]);
      unsigned p23 = pk2r(pe[js][2], pe[js][3]);
      pw[(quad*4+0)*72 + col] = (short)p01;
      pw[(quad*4+1)*72 + col] = (short)(p01>>16);
      pw[(quad*4+2)*72 + col] = (short)p23;
      pw[(quad*4+3)*72 + col] = (short)(p23>>16);
    }
    // PV: 2 j-ksteps x (4 d-subtiles + ones row-sum)
    #pragma unroll
    for(int jk=0;jk<2;jk++){
      s16x8 pf = *(const s16x8*)(pw + l16*72 + jk*32 + quad*8);
      #pragma unroll
      for(int ds=0;ds<4;ds++){
        s16x8 vf = *(const s16x8*)(vb + ((size_t)((jt*4+ds)*2+jk)*64 + lane)*8);
        oacc[ds] = MFMA(pf, vf, oacc[ds]);
      }
      lacc = MFMA(pf, ones, lacc);
    }
  }
  __syncthreads();     // waves done with pw region
  float* comb  = combf;          // [4][16][64]: wave, e, lane
  float* lcomb = combf + 4096;   // [4][16]: wave, il
  #pragma unroll
  for(int e=0;e<16;e++) comb[wave*1024 + e*64 + lane] = oacc[e>>2][e&3];
  if(l16 == 0){
    #pragma unroll
    for(int r=0;r<4;r++) lcomb[wave*16 + quad*4 + r] = lacc[r];
  }
  __syncthreads();
  #pragma unroll
  for(int i=0;i<4;i++){
    int s = i*256 + tid;               // s = e*64 + lsrc
    int e = s >> 6, lsrc = s & 63;
    int ds = e >> 2, rr = e & 3;
    int il = (lsrc >> 4)*4 + rr;
    int dim = ds*16 + (lsrc & 15);
    float o = comb[s] + comb[1024+s] + comb[2048+s] + comb[3072+s];
    float l = lcomb[il] + lcomb[16+il] + lcomb[32+il] + lcomb[48+il];
    out[((size_t)(b*1024 + iw + il)*512) + h*64 + dim] = f2b(o / l);
  }
}

// ---- out projection: fp32 out = a_bf @ Wo^T + bo + x, 64x64 tiles, BK=64 ----
__global__ __launch_bounds__(256) void gemm_out(
    const short* __restrict__ A, const short* __restrict__ B,
    const float* __restrict__ bias, const float* __restrict__ resid,
    float* __restrict__ Cout)
{
  __shared__ __align__(16) short At[64*64];
  __shared__ __align__(16) short Bt[64*64];
  int tid = threadIdx.x;
  int wave = tid >> 6, lane = tid & 63;
  int quad = lane >> 4, l16 = lane & 15;
  int wm = wave >> 1, wn = wave & 1;
  int m0 = blockIdx.y*64, n0 = blockIdx.x*64;
  int sr8 = lane >> 3, sc = (lane & 7)*8;
  f32x4 acc[2][2] = {};
  for(int k0=0; k0<512; k0+=64){
    #pragma unroll
    for(int c=0;c<2;c++){
      int ci = wave*2 + c;                     // chunk: rows ci*8..ci*8+7
      gload_lds16(A + (size_t)(m0 + ci*8 + sr8)*512 + k0 + sc, At + ci*512);
      gload_lds16(B + (size_t)(n0 + ci*8 + sr8)*512 + k0 + sc, Bt + ci*512);
    }
    __syncthreads();
    #pragma unroll
    for(int ks2=0;ks2<2;ks2++){
      s16x8 af[2], bfr[2];
      #pragma unroll
      for(int i=0;i<2;i++) af[i]  = *(const s16x8*)(At + (wm*32 + i*16 + l16)*64 + ks2*32 + quad*8);
      #pragma unroll
      for(int j=0;j<2;j++) bfr[j] = *(const s16x8*)(Bt + (wn*32 + j*16 + l16)*64 + ks2*32 + quad*8);
      #pragma unroll
      for(int i=0;i<2;i++)
        #pragma unroll
        for(int j=0;j<2;j++)
          acc[i][j] = MFMA(af[i], bfr[j], acc[i][j]);
    }
    __syncthreads();
  }
  #pragma unroll
  for(int i=0;i<2;i++){
    int rowb = m0 + wm*32 + i*16 + quad*4;
    #pragma unroll
    for(int j=0;j<2;j++){
      int col = n0 + wn*32 + j*16 + l16;
      float bv = bias[col];
      #pragma unroll
      for(int r=0;r<4;r++){
        size_t idx = (size_t)(rowb + r)*512 + col;
        Cout[idx] = acc[i][j][r] + bv + resid[idx];
      }
    }
  }
}

extern "C" void kernel_launch(void* const* d_in, const int* in_sizes, int n_in,
                              void* d_out, int out_size, void* d_ws, size_t ws_size,
                              hipStream_t stream)
{
  const float* x    = (const float*)d_in[0];
  const float* pos  = (const float*)d_in[1];
  const float* lnw  = (const float*)d_in[2];
  const float* lnb  = (const float*)d_in[3];
  const float* Wq   = (const float*)d_in[4];
  const float* bq   = (const float*)d_in[5];
  const float* Wk   = (const float*)d_in[6];
  const float* bk   = (const float*)d_in[7];
  const float* Wv   = (const float*)d_in[8];
  const float* bv   = (const float*)d_in[9];
  const float* Wo   = (const float*)d_in[10];
  const float* bo   = (const float*)d_in[11];
  const float* Wp   = (const float*)d_in[12];
  const float* pbu  = (const float*)d_in[13];
  const float* pbv  = (const float*)d_in[14];
  float* out = (float*)d_out;

  char* ws = (char*)d_ws;
  short* h_bf    = (short*)(ws);                 // 8192x512
  short* q_sw    = (short*)(ws + ( 8u<<20));     // fragment-major
  short* k_sw    = (short*)(ws + (16u<<20));
  short* v_sw    = (short*)(ws + (24u<<20));
  short* a_bf    = (short*)(ws + (32u<<20));     // attn out, row-major
  short* p_sw    = (short*)(ws + (40u<<20));     // 2 MB
  short* pos_bf  = (short*)(ws + (42u<<20));     // 2 MB
  short* wqkv_bf = (short*)(ws + (44u<<20));     // 3 MB
  short* wo_bf   = (short*)(ws + (47u<<20));     // 0.5 MB
  short* wp_bf   = (short*)(ws + (47u<<20) + (512u<<10));

  prep_kernel<<<dim3(3200), 256, 0, stream>>>(Wq, Wk, Wv, Wo, Wp, pos,
                                              x, lnw, lnb,
                                              wqkv_bf, wo_bf, wp_bf, pos_bf, h_bf);
  gemm_fused<<<dim3(1024), 256, 0, stream>>>(h_bf, wqkv_bf, bq, bk, bv,
                                             pos_bf, wp_bf,
                                             q_sw, k_sw, v_sw, p_sw);
  attn_kernel<<<dim3(64,8,8), 256, 0, stream>>>(q_sw, k_sw, v_sw, p_sw, pbu, pbv, a_bf);
  gemm_out<<<dim3(8,128), 256, 0, stream>>>(a_bf, wo_bf, bo, x, out);
  (void)in_sizes; (void)n_in; (void)out_size; (void)ws_size;
}